// Round 7
// baseline (183.532 us; speedup 1.0000x reference)
//
#include <hip/hip_runtime.h>
#include <hip/hip_bf16.h>
#include <math.h>

// GAT, N=4096, NFEAT=512, NHID=64, NHEADS=8, NCLASS=41, EDGE_P=0.004.
// Adjacency ~17 nnz/row -> both attention layers are exactly sparse.
// gemm1 (x@W_heads) and gemm2 (h@W_out) use bf16 MFMA with split-bf16 (hi+lo)
// 3-term products for fp32-grade accuracy.
// R7: wh_gemm rebuilt as gemm2's proven split-K structure. Diagnosis: every
// prior wh variant (R3/R5/R6, all ~16us) ran 512x128 = 1024 waves = 1
// wave/SIMD -- zero TLP, all latency exposed; source-level pipelining was
// provably neutral. Now: block = 16 rows x 64 cols x 1 head, K split
// 128/wave over 4 waves, grid 2048 blocks = 8192 waves (~4/SIMD with
// launch_bounds(256,4)). Fragments direct from L1/L2 (B = 256 KB/head pinned
// per-XCD via h = id&7 under round-robin dispatch); LDS only for the 12 KB
// cross-wave reduce; ONE barrier. Per-wave K-chain: 4 steps (vs R4's 16).

#define N 4096
#define NFEAT 512
#define NHID 64
#define NHEADS 8
#define NCLASS 41
#define NCPAD 48
#define ALPHA 0.2f
#define ELLW 64   // Binomial(4096,0.004): mean 16.4, P(cnt>64) ~ 1e-18

using short8  = __attribute__((ext_vector_type(8))) short;
using floatx4 = __attribute__((ext_vector_type(4))) float;

__device__ __forceinline__ float wred_max(float v) {
#pragma unroll
  for (int o = 32; o; o >>= 1) v = fmaxf(v, __shfl_xor(v, o, 64));
  return v;
}
__device__ __forceinline__ float wred_sum(float v) {
#pragma unroll
  for (int o = 32; o; o >>= 1) v += __shfl_xor(v, o, 64);
  return v;
}

__device__ __forceinline__ void split_bf16(float v, short& hi, short& lo) {
  __hip_bfloat16 hb = __float2bfloat16(v);
  float hf = __bfloat162float(hb);
  __hip_bfloat16 lb = __float2bfloat16(v - hf);
  hi = *reinterpret_cast<short*>(&hb);
  lo = *reinterpret_cast<short*>(&lb);
}

// ---- setup: adj ELL build + fused prep (x split, W_heads split+T, W_out split+T)
// blocks [0,4096): adj scan (the 64 MB long pole -> dispatched first).
// [4096,6144): x. [6144,6208): W_heads (LDS-tile transpose). [6208,6304): W_out.
__global__ __launch_bounds__(256) void setup(const float* __restrict__ x,
                                             const float* __restrict__ W,
                                             const float* __restrict__ W_out,
                                             const float* __restrict__ adj,
                                             short* __restrict__ Xhi,
                                             short* __restrict__ Xlo,
                                             short* __restrict__ Wthi,
                                             short* __restrict__ Wtlo,
                                             short* __restrict__ WOhi,
                                             short* __restrict__ WOlo,
                                             int* __restrict__ cols,
                                             int* __restrict__ cnts) {
  if (blockIdx.x < 4096) {
    // -------- build ELL neighbor lists
    __shared__ int c;
    const int row = blockIdx.x;
    if (threadIdx.x == 0) c = 0;
    __syncthreads();
    const float4* arow = (const float4*)(adj + (size_t)row * N);
    for (int j4 = threadIdx.x; j4 < N / 4; j4 += 256) {
      float4 v = arow[j4];
      if (v.x > 0.f) { int p = atomicAdd(&c, 1); if (p < ELLW) cols[row * ELLW + p] = j4 * 4 + 0; }
      if (v.y > 0.f) { int p = atomicAdd(&c, 1); if (p < ELLW) cols[row * ELLW + p] = j4 * 4 + 1; }
      if (v.z > 0.f) { int p = atomicAdd(&c, 1); if (p < ELLW) cols[row * ELLW + p] = j4 * 4 + 2; }
      if (v.w > 0.f) { int p = atomicAdd(&c, 1); if (p < ELLW) cols[row * ELLW + p] = j4 * 4 + 3; }
    }
    __syncthreads();
    if (threadIdx.x == 0) cnts[row] = min(c, ELLW);
  } else if (blockIdx.x < 6144) {
    const int t = (blockIdx.x - 4096) * 256 + threadIdx.x;  // float4 index
    const float4 v = ((const float4*)x)[t];
    short h0, l0, h1, l1, h2, l2, h3, l3;
    split_bf16(v.x, h0, l0);
    split_bf16(v.y, h1, l1);
    split_bf16(v.z, h2, l2);
    split_bf16(v.w, h3, l3);
    ((short4*)Xhi)[t] = make_short4(h0, h1, h2, h3);
    ((short4*)Xlo)[t] = make_short4(l0, l1, l2, l3);
  } else if (blockIdx.x < 6208) {
    // -------- W_heads transpose+split via LDS tile (coalesced both ways).
    // Block handles one (head h, 64-wide k chunk): tile = W[h][k0..k0+63][0..63].
    __shared__ float tile[64][65];
    const int idx = blockIdx.x - 6144;
    const int h = idx >> 3, k0 = (idx & 7) * 64;
    const int t = threadIdx.x;
#pragma unroll
    for (int i = 0; i < 4; i++) {
      const int g = t + 256 * i;                 // 1024 float4 granules
      const int r = g >> 4, c4 = g & 15;
      const float4 v = *(const float4*)&W[(size_t)h * 32768 + (size_t)(k0 + r) * 64 + c4 * 4];
      tile[r][c4 * 4 + 0] = v.x;
      tile[r][c4 * 4 + 1] = v.y;
      tile[r][c4 * 4 + 2] = v.z;
      tile[r][c4 * 4 + 3] = v.w;
    }
    __syncthreads();
#pragma unroll
    for (int i = 0; i < 2; i++) {
      const int g = t + 256 * i;                 // 512 out granules (64 d x 8 kg)
      const int d = g >> 3, kg = (g & 7) * 8;
      short8 hv, lv;
#pragma unroll
      for (int j = 0; j < 8; j++) {
        short hh, ll;
        split_bf16(tile[kg + j][d], hh, ll);
        hv[j] = hh;
        lv[j] = ll;
      }
      const size_t dst = (size_t)h * 32768 + (size_t)d * 512 + k0 + kg;
      *(short8*)&Wthi[dst] = hv;
      *(short8*)&Wtlo[dst] = lv;
    }
  } else {
    const int t = (blockIdx.x - 6208) * 256 + threadIdx.x;  // 0..24575
    const int c = t >> 9, k = t & 511;
    float v = (c < NCLASS) ? W_out[(size_t)k * NCLASS + c] : 0.f;
    short hi, lo;
    split_bf16(v, hi, lo);
    WOhi[c * 512 + k] = hi;
    WOlo[c * 512 + k] = lo;
  }
}

// ----------------- Wh = x @ W_heads via split-bf16 MFMA; fused s1/s2 epilogue
// gemm2-style split-K: 2048 blocks (= 256 row-tiles x 8 heads) x 256 threads;
// block computes rows [n0,n0+16) x all 64 cols for head h = id&7 (same-head
// blocks share one XCD's L2 -> B 256 KB resident). K=512 split 128/wave;
// A/B fragments read straight from L1/L2 (16 rows x 64B coalesced); LDS only
// for the 4-way cross-wave reduce; one barrier.
__global__ __launch_bounds__(256, 4) void wh_gemm_mfma(
    const short* __restrict__ Xhi, const short* __restrict__ Xlo,
    const short* __restrict__ Wthi, const short* __restrict__ Wtlo,
    const float* __restrict__ a_heads,
    float* __restrict__ Wh, float* __restrict__ s1, float* __restrict__ s2) {
  __shared__ float red[3][64][16];
  const int id = blockIdx.x;
  const int h = id & 7;              // round-robin dispatch -> head pinned per XCD
  const int n0 = (id >> 3) * 16;     // 16-row tile
  const int w = threadIdx.x >> 6, L = threadIdx.x & 63;
  const int q = L >> 4, r15 = L & 15;

  floatx4 acc[4];
#pragma unroll
  for (int f = 0; f < 4; f++) acc[f] = (floatx4){0.f, 0.f, 0.f, 0.f};

  const short* Ah = Xhi + (size_t)(n0 + r15) * NFEAT;
  const short* Al = Xlo + (size_t)(n0 + r15) * NFEAT;
  const short* Bh = Wthi + (size_t)h * 32768 + (size_t)r15 * 512;
  const short* Bl = Wtlo + (size_t)h * 32768 + (size_t)r15 * 512;

#pragma unroll 2
  for (int ks = 0; ks < 4; ks++) {
    const int ko = w * 128 + ks * 32 + q * 8;
    const short8 ahi = *(const short8*)&Ah[ko];
    const short8 alo = *(const short8*)&Al[ko];
#pragma unroll
    for (int f = 0; f < 4; f++) {
      const short8 bhi = *(const short8*)&Bh[f * 16 * 512 + ko];
      const short8 blo = *(const short8*)&Bl[f * 16 * 512 + ko];
      acc[f] = __builtin_amdgcn_mfma_f32_16x16x32_bf16(ahi, bhi, acc[f], 0, 0, 0);
      acc[f] = __builtin_amdgcn_mfma_f32_16x16x32_bf16(ahi, blo, acc[f], 0, 0, 0);
      acc[f] = __builtin_amdgcn_mfma_f32_16x16x32_bf16(alo, bhi, acc[f], 0, 0, 0);
    }
  }

  if (w) {
#pragma unroll
    for (int f = 0; f < 4; f++)
#pragma unroll
      for (int r = 0; r < 4; r++) red[w - 1][L][f * 4 + r] = acc[f][r];
  }
  __syncthreads();
  if (w == 0) {
    const int c16 = r15;
    float a1v[4], a2v[4];
#pragma unroll
    for (int f = 0; f < 4; f++) {
      a1v[f] = a_heads[h * 128 + f * 16 + c16];
      a2v[f] = a_heads[h * 128 + 64 + f * 16 + c16];
    }
    float p1[4] = {0.f, 0.f, 0.f, 0.f}, p2[4] = {0.f, 0.f, 0.f, 0.f};
#pragma unroll
    for (int f = 0; f < 4; f++)
#pragma unroll
      for (int r = 0; r < 4; r++) {
        const float vv = acc[f][r] + red[0][L][f * 4 + r] + red[1][L][f * 4 + r] +
                         red[2][L][f * 4 + r];
        const int row = n0 + q * 4 + r;
        Wh[((size_t)(h << 12) + row) * NHID + f * 16 + c16] = vv;
        p1[r] += vv * a1v[f];
        p2[r] += vv * a2v[f];
      }
#pragma unroll
    for (int r = 0; r < 4; r++)
#pragma unroll
      for (int o = 1; o < 16; o <<= 1) {
        p1[r] += __shfl_xor(p1[r], o, 64);
        p2[r] += __shfl_xor(p2[r], o, 64);
      }
    if (c16 == 0) {
      const int row = n0 + q * 4;
#pragma unroll
      for (int r = 0; r < 4; r++) {
        s1[(h << 12) + row + r] = p1[r];
        s2[(h << 12) + row + r] = p2[r];
      }
    }
  }
}

// ---- layer-1 attention: wave per (i,h); 8-neighbor-parallel gather
//      (8 lanes x 2 float4 per neighbor); ELU; emit h as split bf16
//      (Hhi/Hlo) laid out [node][head*64+d].
__global__ __launch_bounds__(256) void att1_kernel(
    const float* __restrict__ Wh, const float* __restrict__ s1,
    const float* __restrict__ s2, const int* __restrict__ cols,
    const int* __restrict__ cnts, short* __restrict__ Hhi,
    short* __restrict__ Hlo) {
  __shared__ float pj[4][64];
  __shared__ int jj[4][64];
  const int w = threadIdx.x >> 6, lane = threadIdx.x & 63;
  const int pair = blockIdx.x * 4 + w;
  const int h = pair >> 12, i = pair & (N - 1);
  const int cnt = cnts[i];
  const float s1i = s1[(h << 12) + i];
  const float* s2h = s2 + (h << 12);
  float e0 = -1e30f;
  int j0 = 0;
  if (lane < cnt) {
    j0 = cols[i * ELLW + lane];
    float t = s1i + s2h[j0];
    e0 = t > 0.f ? t : ALPHA * t;
  }
  const float m = wred_max(e0);
  float p = (lane < cnt) ? expf(e0 - m) : 0.f;
  const float S = wred_sum(p);
  p *= 1.f / S;                       // lanes >= cnt hold exactly 0
  pj[w][lane] = p;
  jj[w][lane] = (lane < cnt) ? j0 : 0;
  __syncthreads();
  // gather: 8 neighbors in flight; group grp handles neighbor t0+grp,
  // its 8 lanes load 2 float4 slices of the 64-float Wh row (2x128 B/group).
  // cnt <= 64 and grp <= 7 -> t0+grp <= 63, and p=0 past cnt: no tail logic.
  const int grp = lane >> 3, c8 = lane & 7;
  const float* Whh = Wh + (((size_t)h << 12)) * NHID;
  float4 a0 = make_float4(0.f, 0.f, 0.f, 0.f);
  float4 a1 = make_float4(0.f, 0.f, 0.f, 0.f);
  for (int t0 = 0; t0 < cnt; t0 += 8) {
    const float pt = pj[w][t0 + grp];
    const int jt = jj[w][t0 + grp];
    const float4 v0 = *(const float4*)&Whh[(size_t)jt * NHID + c8 * 8];
    const float4 v1 = *(const float4*)&Whh[(size_t)jt * NHID + c8 * 8 + 4];
    a0.x += pt * v0.x; a0.y += pt * v0.y; a0.z += pt * v0.z; a0.w += pt * v0.w;
    a1.x += pt * v1.x; a1.y += pt * v1.y; a1.z += pt * v1.z; a1.w += pt * v1.w;
  }
#pragma unroll
  for (int off = 8; off <= 32; off <<= 1) {
    a0.x += __shfl_xor(a0.x, off, 64);
    a0.y += __shfl_xor(a0.y, off, 64);
    a0.z += __shfl_xor(a0.z, off, 64);
    a0.w += __shfl_xor(a0.w, off, 64);
    a1.x += __shfl_xor(a1.x, off, 64);
    a1.y += __shfl_xor(a1.y, off, 64);
    a1.z += __shfl_xor(a1.z, off, 64);
    a1.w += __shfl_xor(a1.w, off, 64);
  }
  if (grp == 0) {
    float o[8] = {a0.x, a0.y, a0.z, a0.w, a1.x, a1.y, a1.z, a1.w};
    short8 hv, lv;
#pragma unroll
    for (int j = 0; j < 8; j++) {
      const float e = o[j] > 0.f ? o[j] : expf(o[j]) - 1.f;  // ELU
      short hh, ll;
      split_bf16(e, hh, ll);
      hv[j] = hh;
      lv[j] = ll;
    }
    const size_t base = (size_t)i * 512 + h * 64 + c8 * 8;
    *(short8*)&Hhi[base] = hv;
    *(short8*)&Hlo[base] = lv;
  }
}

// ---- gemm2: Wh2 = h @ W_out (split-bf16 MFMA, cols padded to 48);
//      fused s1b/s2b = Wh2 . a_out halves.
// 256 blocks x 16 rows; K=512 split 128-per-wave; A/B fragments read straight
// from L2 (16 rows x 64B contiguous segments -> fully coalesced); LDS only
// holds the 4-way cross-wave partial reduction. No staging barriers.
__global__ __launch_bounds__(256) void gemm2_mfma(
    const short* __restrict__ Hhi, const short* __restrict__ Hlo,
    const short* __restrict__ WOhi, const short* __restrict__ WOlo,
    const float* __restrict__ a_out,
    float* __restrict__ Wh2, float* __restrict__ s1b, float* __restrict__ s2b) {
  __shared__ float red[3][64][12];
  const int n0 = blockIdx.x * 16;
  const int tid = threadIdx.x;
  const int w = tid >> 6, L = tid & 63;
  const int r15 = L & 15;

  floatx4 acc[3];
#pragma unroll
  for (int f = 0; f < 3; f++) acc[f] = (floatx4){0.f, 0.f, 0.f, 0.f};

#pragma unroll
  for (int ks = 0; ks < 4; ks++) {
    const int koff = w * 128 + ks * 32 + (L >> 4) * 8;
    const short8 ahi = *(const short8*)&Hhi[(size_t)(n0 + r15) * 512 + koff];
    const short8 alo = *(const short8*)&Hlo[(size_t)(n0 + r15) * 512 + koff];
#pragma unroll
    for (int f = 0; f < 3; f++) {
      const short8 bhi = *(const short8*)&WOhi[(size_t)(f * 16 + r15) * 512 + koff];
      const short8 blo = *(const short8*)&WOlo[(size_t)(f * 16 + r15) * 512 + koff];
      acc[f] = __builtin_amdgcn_mfma_f32_16x16x32_bf16(ahi, bhi, acc[f], 0, 0, 0);
      acc[f] = __builtin_amdgcn_mfma_f32_16x16x32_bf16(ahi, blo, acc[f], 0, 0, 0);
      acc[f] = __builtin_amdgcn_mfma_f32_16x16x32_bf16(alo, bhi, acc[f], 0, 0, 0);
    }
  }

  if (w) {
#pragma unroll
    for (int f = 0; f < 3; f++)
#pragma unroll
      for (int r = 0; r < 4; r++) red[w - 1][L][f * 4 + r] = acc[f][r];
  }
  __syncthreads();
  if (w == 0) {
    const int q = L >> 4, c16 = r15;
    float a1v[3], a2v[3];
#pragma unroll
    for (int f = 0; f < 3; f++) {
      const int col = f * 16 + c16;
      a1v[f] = (col < NCLASS) ? a_out[col] : 0.f;
      a2v[f] = (col < NCLASS) ? a_out[NCLASS + col] : 0.f;
    }
    float p1[4] = {0.f, 0.f, 0.f, 0.f}, p2[4] = {0.f, 0.f, 0.f, 0.f};
#pragma unroll
    for (int f = 0; f < 3; f++)
#pragma unroll
      for (int r = 0; r < 4; r++) {
        const float vv = acc[f][r] + red[0][L][f * 4 + r] + red[1][L][f * 4 + r] +
                         red[2][L][f * 4 + r];
        const int col = f * 16 + c16;
        const int row = n0 + q * 4 + r;
        if (col < NCLASS) Wh2[(size_t)row * NCLASS + col] = vv;
        p1[r] += vv * a1v[f];
        p2[r] += vv * a2v[f];
      }
#pragma unroll
    for (int r = 0; r < 4; r++)
#pragma unroll
      for (int o = 1; o < 16; o <<= 1) {
        p1[r] += __shfl_xor(p1[r], o, 64);
        p2[r] += __shfl_xor(p2[r], o, 64);
      }
    if (c16 == 0) {
      const int row = n0 + q * 4;
#pragma unroll
      for (int r = 0; r < 4; r++) {
        s1b[row + r] = p1[r];
        s2b[row + r] = p2[r];
      }
    }
  }
}

// ----------------- layer-2 sparse attention + ELU + log_softmax -> out (fp32)
__global__ __launch_bounds__(256) void att2_kernel(const float* __restrict__ Wh2,
                                                   const float* __restrict__ s1b,
                                                   const float* __restrict__ s2b,
                                                   const int* __restrict__ cols,
                                                   const int* __restrict__ cnts,
                                                   float* __restrict__ out) {
  __shared__ float pj[4][64];
  __shared__ int jj[4][64];
  const int w = threadIdx.x >> 6, lane = threadIdx.x & 63;
  const int i = blockIdx.x * 4 + w;
  const int cnt = cnts[i];
  const float s1i = s1b[i];
  float e0 = -1e30f;
  int j0 = 0;
  if (lane < cnt) {
    j0 = cols[i * ELLW + lane];
    float t = s1i + s2b[j0];
    e0 = t > 0.f ? t : ALPHA * t;
  }
  const float m = wred_max(e0);
  float p = (lane < cnt) ? expf(e0 - m) : 0.f;
  const float S = wred_sum(p);
  p *= 1.f / S;
  pj[w][lane] = p;
  jj[w][lane] = (lane < cnt) ? j0 : 0;
  __syncthreads();
  float acc = 0.f;
  for (int t = 0; t < cnt; t++) {
    const float pt = pj[w][t];
    const int jt = jj[w][t];
    if (lane < NCLASS) acc += pt * Wh2[(size_t)jt * NCLASS + lane];
  }
  const float o = acc > 0.f ? acc : expf(acc) - 1.f;  // ELU
  const float vv = (lane < NCLASS) ? o : -1e30f;
  const float mm = wred_max(vv);
  const float ex = (lane < NCLASS) ? expf(o - mm) : 0.f;
  const float SS = wred_sum(ex);
  if (lane < NCLASS) out[(size_t)i * NCLASS + lane] = o - mm - logf(SS);
}

// ---------------------------------------------------------------------------
extern "C" void kernel_launch(void* const* d_in, const int* in_sizes, int n_in,
                              void* d_out, int out_size, void* d_ws, size_t ws_size,
                              hipStream_t stream) {
  const float* x       = (const float*)d_in[0];   // (4096, 512)
  const float* adj     = (const float*)d_in[1];   // (4096, 4096)
  const float* W_heads = (const float*)d_in[2];   // (8, 512, 64)
  const float* a_heads = (const float*)d_in[3];   // (8, 128, 1)
  const float* W_out   = (const float*)d_in[4];   // (512, 41)
  const float* a_out   = (const float*)d_in[5];   // (82, 1)
  float* out = (float*)d_out;                     // (4096, 41)

  // workspace layout (~29 MB)
  float* ws   = (float*)d_ws;
  float* Wh   = ws;                                  // 8*4096*64
  float* s1   = Wh + (size_t)NHEADS * N * NHID;      // 8*4096
  float* s2   = s1 + NHEADS * N;                     // 8*4096
  float* Wh2  = s2 + NHEADS * N;                     // 4096*41
  float* s1b  = Wh2 + (size_t)N * NCLASS;            // 4096
  float* s2b  = s1b + N;                             // 4096
  int* cnts   = (int*)(s2b + N);                     // 4096
  int* cols   = cnts + N;                            // 4096*64
  short* Xhi  = (short*)(cols + N * ELLW);           // 4096*512
  short* Xlo  = Xhi + (size_t)N * NFEAT;             // 4096*512
  short* Wthi = Xlo + (size_t)N * NFEAT;             // 8*64*512
  short* Wtlo = Wthi + (size_t)NHEADS * NHID * NFEAT;// 8*64*512
  short* WOhi = Wtlo + (size_t)NHEADS * NHID * NFEAT;// 48*512
  short* WOlo = WOhi + (size_t)NCPAD * 512;          // 48*512
  short* Hhi  = WOlo + (size_t)NCPAD * 512;          // 4096*512
  short* Hlo  = Hhi + (size_t)N * NFEAT;             // 4096*512

  hipLaunchKernelGGL(setup, dim3(6304), dim3(256), 0, stream,
                     x, W_heads, W_out, adj, Xhi, Xlo, Wthi, Wtlo, WOhi, WOlo, cols, cnts);
  hipLaunchKernelGGL(wh_gemm_mfma, dim3(NHEADS * N / 16), dim3(256), 0, stream,
                     Xhi, Xlo, Wthi, Wtlo, a_heads, Wh, s1, s2);
  hipLaunchKernelGGL(att1_kernel, dim3(NHEADS * N / 4), dim3(256), 0, stream,
                     Wh, s1, s2, cols, cnts, Hhi, Hlo);
  hipLaunchKernelGGL(gemm2_mfma, dim3(N / 16), dim3(256), 0, stream,
                     Hhi, Hlo, WOhi, WOlo, a_out, Wh2, s1b, s2b);
  hipLaunchKernelGGL(att2_kernel, dim3(N / 4), dim3(256), 0, stream,
                     Wh2, s1b, s2b, cols, cnts, out);
}

// Round 8
// 158.864 us; speedup vs baseline: 1.1553x; 1.1553x over previous
//
#include <hip/hip_runtime.h>
#include <hip/hip_bf16.h>
#include <math.h>

// GAT, N=4096, NFEAT=512, NHID=64, NHEADS=8, NCLASS=41, EDGE_P=0.004.
// Adjacency ~17 nnz/row -> both attention layers are exactly sparse.
// gemm1 (x@W_heads) and gemm2 (h@W_out) use bf16 MFMA with split-bf16 (hi+lo)
// 3-term products for fp32-grade accuracy.
// R8: REVERT to the proven best (R5, 159.6us). R7's split-K wh_gemm was a
// catastrophe (20.3ms profiled, 34GB FETCH: 4x B re-fetch amplification +
// A shared across 8 head-blocks with no co-residency -> L2 thrash).
// Session findings (R3-R7): wh_gemm ~16us is invariant under barrier count,
// dbuf pipelining, LDS-op reduction, and occupancy changes; it collapses when
// operands lose cache residency. The N=64 GEMM shape structurally caps MFMA
// reuse; the remaining ~10us stall resisted 5 distinct mechanisms.
// Timed-region budget: ~111us harness re-poison fills (80% HBM peak, not
// controllable from this file) + setup ~15 (at HBM roofline) + wh ~16 +
// att1 ~7 + gemm2 ~6 + att2 ~3.

#define N 4096
#define NFEAT 512
#define NHID 64
#define NHEADS 8
#define NCLASS 41
#define NCPAD 48
#define ALPHA 0.2f
#define ELLW 64   // Binomial(4096,0.004): mean 16.4, P(cnt>64) ~ 1e-18

using short8  = __attribute__((ext_vector_type(8))) short;
using floatx4 = __attribute__((ext_vector_type(4))) float;

__device__ __forceinline__ float wred_max(float v) {
#pragma unroll
  for (int o = 32; o; o >>= 1) v = fmaxf(v, __shfl_xor(v, o, 64));
  return v;
}
__device__ __forceinline__ float wred_sum(float v) {
#pragma unroll
  for (int o = 32; o; o >>= 1) v += __shfl_xor(v, o, 64);
  return v;
}

__device__ __forceinline__ void split_bf16(float v, short& hi, short& lo) {
  __hip_bfloat16 hb = __float2bfloat16(v);
  float hf = __bfloat162float(hb);
  __hip_bfloat16 lb = __float2bfloat16(v - hf);
  hi = *reinterpret_cast<short*>(&hb);
  lo = *reinterpret_cast<short*>(&lb);
}

// ---- setup: adj ELL build + fused prep (x split, W_heads split+T, W_out split+T)
// blocks [0,4096): adj scan (the 64 MB long pole -> dispatched first).
// [4096,6144): x. [6144,6208): W_heads (LDS-tile transpose). [6208,6304): W_out.
__global__ __launch_bounds__(256) void setup(const float* __restrict__ x,
                                             const float* __restrict__ W,
                                             const float* __restrict__ W_out,
                                             const float* __restrict__ adj,
                                             short* __restrict__ Xhi,
                                             short* __restrict__ Xlo,
                                             short* __restrict__ Wthi,
                                             short* __restrict__ Wtlo,
                                             short* __restrict__ WOhi,
                                             short* __restrict__ WOlo,
                                             int* __restrict__ cols,
                                             int* __restrict__ cnts) {
  if (blockIdx.x < 4096) {
    // -------- build ELL neighbor lists
    __shared__ int c;
    const int row = blockIdx.x;
    if (threadIdx.x == 0) c = 0;
    __syncthreads();
    const float4* arow = (const float4*)(adj + (size_t)row * N);
    for (int j4 = threadIdx.x; j4 < N / 4; j4 += 256) {
      float4 v = arow[j4];
      if (v.x > 0.f) { int p = atomicAdd(&c, 1); if (p < ELLW) cols[row * ELLW + p] = j4 * 4 + 0; }
      if (v.y > 0.f) { int p = atomicAdd(&c, 1); if (p < ELLW) cols[row * ELLW + p] = j4 * 4 + 1; }
      if (v.z > 0.f) { int p = atomicAdd(&c, 1); if (p < ELLW) cols[row * ELLW + p] = j4 * 4 + 2; }
      if (v.w > 0.f) { int p = atomicAdd(&c, 1); if (p < ELLW) cols[row * ELLW + p] = j4 * 4 + 3; }
    }
    __syncthreads();
    if (threadIdx.x == 0) cnts[row] = min(c, ELLW);
  } else if (blockIdx.x < 6144) {
    const int t = (blockIdx.x - 4096) * 256 + threadIdx.x;  // float4 index
    const float4 v = ((const float4*)x)[t];
    short h0, l0, h1, l1, h2, l2, h3, l3;
    split_bf16(v.x, h0, l0);
    split_bf16(v.y, h1, l1);
    split_bf16(v.z, h2, l2);
    split_bf16(v.w, h3, l3);
    ((short4*)Xhi)[t] = make_short4(h0, h1, h2, h3);
    ((short4*)Xlo)[t] = make_short4(l0, l1, l2, l3);
  } else if (blockIdx.x < 6208) {
    // -------- W_heads transpose+split via LDS tile (coalesced both ways).
    // Block handles one (head h, 64-wide k chunk): tile = W[h][k0..k0+63][0..63].
    __shared__ float tile[64][65];
    const int idx = blockIdx.x - 6144;
    const int h = idx >> 3, k0 = (idx & 7) * 64;
    const int t = threadIdx.x;
#pragma unroll
    for (int i = 0; i < 4; i++) {
      const int g = t + 256 * i;                 // 1024 float4 granules
      const int r = g >> 4, c4 = g & 15;
      const float4 v = *(const float4*)&W[(size_t)h * 32768 + (size_t)(k0 + r) * 64 + c4 * 4];
      tile[r][c4 * 4 + 0] = v.x;
      tile[r][c4 * 4 + 1] = v.y;
      tile[r][c4 * 4 + 2] = v.z;
      tile[r][c4 * 4 + 3] = v.w;
    }
    __syncthreads();
#pragma unroll
    for (int i = 0; i < 2; i++) {
      const int g = t + 256 * i;                 // 512 out granules (64 d x 8 kg)
      const int d = g >> 3, kg = (g & 7) * 8;
      short8 hv, lv;
#pragma unroll
      for (int j = 0; j < 8; j++) {
        short hh, ll;
        split_bf16(tile[kg + j][d], hh, ll);
        hv[j] = hh;
        lv[j] = ll;
      }
      const size_t dst = (size_t)h * 32768 + (size_t)d * 512 + k0 + kg;
      *(short8*)&Wthi[dst] = hv;
      *(short8*)&Wtlo[dst] = lv;
    }
  } else {
    const int t = (blockIdx.x - 6208) * 256 + threadIdx.x;  // 0..24575
    const int c = t >> 9, k = t & 511;
    float v = (c < NCLASS) ? W_out[(size_t)k * NCLASS + c] : 0.f;
    short hi, lo;
    split_bf16(v, hi, lo);
    WOhi[c * 512 + k] = hi;
    WOlo[c * 512 + k] = lo;
  }
}

// ----------------- Wh = x @ W_heads via split-bf16 MFMA; fused s1/s2 epilogue
// 512 blocks x 128 threads (2 waves); wave tile 32x64; double-buffered LDS,
// ONE barrier per K-step, next-tile loads issued before current MFMAs.
// XCD-swizzled: id = (t&7) + 8h + 64(t>>3) puts all 8 heads of a row-tile on
// one XCD (A-tile reused 8x from L2; B set 1 MB stays resident).
__global__ __launch_bounds__(128) void wh_gemm_mfma(
    const short* __restrict__ Xhi, const short* __restrict__ Xlo,
    const short* __restrict__ Wthi, const short* __restrict__ Wtlo,
    const float* __restrict__ a_heads,
    float* __restrict__ Wh, float* __restrict__ s1, float* __restrict__ s2) {
  __shared__ __align__(16) short Ahi[2][64 * 72];
  __shared__ __align__(16) short Alo[2][64 * 72];
  __shared__ __align__(16) short Bhi[2][64 * 72];
  __shared__ __align__(16) short Blo[2][64 * 72];
  const int id = blockIdx.x;
  const int h = (id >> 3) & 7;
  const int tile = (id & 7) + ((id >> 6) << 3);
  const int n0 = tile * 64;
  const int tid = threadIdx.x;
  const int w = tid >> 6, L = tid & 63;

  floatx4 acc[2][4];
#pragma unroll
  for (int rt = 0; rt < 2; rt++)
#pragma unroll
    for (int f = 0; f < 4; f++) acc[rt][f] = (floatx4){0.f, 0.f, 0.f, 0.f};

  // staging granule map: g = tid + 128*i -> (row = g>>3, kg = (g&7)*8)
  uint4 rAhi[4], rAlo[4], rBhi[4], rBlo[4];

#define STAGE_LOAD(K0)                                                       \
  {                                                                          \
    _Pragma("unroll") for (int i = 0; i < 4; i++) {                          \
      const int g = tid + 128 * i;                                           \
      const int row = g >> 3, kg = (g & 7) * 8;                              \
      const size_t asrc = (size_t)(n0 + row) * NFEAT + (K0) + kg;            \
      rAhi[i] = *(const uint4*)&Xhi[asrc];                                   \
      rAlo[i] = *(const uint4*)&Xlo[asrc];                                   \
      const size_t bsrc = (size_t)h * 32768 + (size_t)row * 512 + (K0) + kg; \
      rBhi[i] = *(const uint4*)&Wthi[bsrc];                                  \
      rBlo[i] = *(const uint4*)&Wtlo[bsrc];                                  \
    }                                                                        \
  }

#define STAGE_WRITE(BUF)                                                     \
  {                                                                          \
    _Pragma("unroll") for (int i = 0; i < 4; i++) {                          \
      const int g = tid + 128 * i;                                           \
      const int row = g >> 3, kg = (g & 7) * 8;                              \
      *(uint4*)&Ahi[BUF][row * 72 + kg] = rAhi[i];                           \
      *(uint4*)&Alo[BUF][row * 72 + kg] = rAlo[i];                           \
      *(uint4*)&Bhi[BUF][row * 72 + kg] = rBhi[i];                           \
      *(uint4*)&Blo[BUF][row * 72 + kg] = rBlo[i];                           \
    }                                                                        \
  }

  // prologue: stage tile 0 into buf 0
  STAGE_LOAD(0);
  STAGE_WRITE(0);
  __syncthreads();

  int cur = 0;
  for (int kt = 0; kt < 8; kt++) {
    // issue next tile's global loads first: latency hides under compute
    if (kt < 7) STAGE_LOAD((kt + 1) * 64);
    // compute on buf[cur]
#pragma unroll
    for (int ks = 0; ks < 2; ks++) {
      const int koff = ks * 32 + (L >> 4) * 8;
      const int abase = (w * 32 + (L & 15)) * 72 + koff;
      short8 ahi0 = *(const short8*)&Ahi[cur][abase];
      short8 alo0 = *(const short8*)&Alo[cur][abase];
      short8 ahi1 = *(const short8*)&Ahi[cur][abase + 16 * 72];
      short8 alo1 = *(const short8*)&Alo[cur][abase + 16 * 72];
#pragma unroll
      for (int f = 0; f < 4; f++) {
        short8 bhi = *(const short8*)&Bhi[cur][(f * 16 + (L & 15)) * 72 + koff];
        short8 blo = *(const short8*)&Blo[cur][(f * 16 + (L & 15)) * 72 + koff];
        acc[0][f] = __builtin_amdgcn_mfma_f32_16x16x32_bf16(ahi0, bhi, acc[0][f], 0, 0, 0);
        acc[0][f] = __builtin_amdgcn_mfma_f32_16x16x32_bf16(ahi0, blo, acc[0][f], 0, 0, 0);
        acc[0][f] = __builtin_amdgcn_mfma_f32_16x16x32_bf16(alo0, bhi, acc[0][f], 0, 0, 0);
        acc[1][f] = __builtin_amdgcn_mfma_f32_16x16x32_bf16(ahi1, bhi, acc[1][f], 0, 0, 0);
        acc[1][f] = __builtin_amdgcn_mfma_f32_16x16x32_bf16(ahi1, blo, acc[1][f], 0, 0, 0);
        acc[1][f] = __builtin_amdgcn_mfma_f32_16x16x32_bf16(alo1, bhi, acc[1][f], 0, 0, 0);
      }
    }
    // write next tile into the other buffer; one barrier orders write->read
    if (kt < 7) {
      STAGE_WRITE(cur ^ 1);
      __syncthreads();
    }
    cur ^= 1;
  }
#undef STAGE_LOAD
#undef STAGE_WRITE

  const int q = L >> 4, c16 = L & 15;
  float a1v[4], a2v[4];
#pragma unroll
  for (int f = 0; f < 4; f++) {
    a1v[f] = a_heads[h * 128 + f * 16 + c16];
    a2v[f] = a_heads[h * 128 + 64 + f * 16 + c16];
  }
#pragma unroll
  for (int rt = 0; rt < 2; rt++) {
    float p1[4] = {0.f, 0.f, 0.f, 0.f}, p2[4] = {0.f, 0.f, 0.f, 0.f};
#pragma unroll
    for (int f = 0; f < 4; f++)
#pragma unroll
      for (int r = 0; r < 4; r++) {
        const float vv = acc[rt][f][r];
        const int row = n0 + w * 32 + rt * 16 + q * 4 + r;
        Wh[((size_t)(h << 12) + row) * NHID + f * 16 + c16] = vv;
        p1[r] += vv * a1v[f];
        p2[r] += vv * a2v[f];
      }
#pragma unroll
    for (int r = 0; r < 4; r++)
#pragma unroll
      for (int o = 1; o < 16; o <<= 1) {
        p1[r] += __shfl_xor(p1[r], o, 64);
        p2[r] += __shfl_xor(p2[r], o, 64);
      }
    if (c16 == 0) {
      const int row = n0 + w * 32 + rt * 16 + q * 4;
#pragma unroll
      for (int r = 0; r < 4; r++) {
        s1[(h << 12) + row + r] = p1[r];
        s2[(h << 12) + row + r] = p2[r];
      }
    }
  }
}

// ---- layer-1 attention: wave per (i,h); 8-neighbor-parallel gather
//      (8 lanes x 2 float4 per neighbor); ELU; emit h as split bf16
//      (Hhi/Hlo) laid out [node][head*64+d].
__global__ __launch_bounds__(256) void att1_kernel(
    const float* __restrict__ Wh, const float* __restrict__ s1,
    const float* __restrict__ s2, const int* __restrict__ cols,
    const int* __restrict__ cnts, short* __restrict__ Hhi,
    short* __restrict__ Hlo) {
  __shared__ float pj[4][64];
  __shared__ int jj[4][64];
  const int w = threadIdx.x >> 6, lane = threadIdx.x & 63;
  const int pair = blockIdx.x * 4 + w;
  const int h = pair >> 12, i = pair & (N - 1);
  const int cnt = cnts[i];
  const float s1i = s1[(h << 12) + i];
  const float* s2h = s2 + (h << 12);
  float e0 = -1e30f;
  int j0 = 0;
  if (lane < cnt) {
    j0 = cols[i * ELLW + lane];
    float t = s1i + s2h[j0];
    e0 = t > 0.f ? t : ALPHA * t;
  }
  const float m = wred_max(e0);
  float p = (lane < cnt) ? expf(e0 - m) : 0.f;
  const float S = wred_sum(p);
  p *= 1.f / S;                       // lanes >= cnt hold exactly 0
  pj[w][lane] = p;
  jj[w][lane] = (lane < cnt) ? j0 : 0;
  __syncthreads();
  // gather: 8 neighbors in flight; group grp handles neighbor t0+grp,
  // its 8 lanes load 2 float4 slices of the 64-float Wh row (2x128 B/group).
  // cnt <= 64 and grp <= 7 -> t0+grp <= 63, and p=0 past cnt: no tail logic.
  const int grp = lane >> 3, c8 = lane & 7;
  const float* Whh = Wh + (((size_t)h << 12)) * NHID;
  float4 a0 = make_float4(0.f, 0.f, 0.f, 0.f);
  float4 a1 = make_float4(0.f, 0.f, 0.f, 0.f);
  for (int t0 = 0; t0 < cnt; t0 += 8) {
    const float pt = pj[w][t0 + grp];
    const int jt = jj[w][t0 + grp];
    const float4 v0 = *(const float4*)&Whh[(size_t)jt * NHID + c8 * 8];
    const float4 v1 = *(const float4*)&Whh[(size_t)jt * NHID + c8 * 8 + 4];
    a0.x += pt * v0.x; a0.y += pt * v0.y; a0.z += pt * v0.z; a0.w += pt * v0.w;
    a1.x += pt * v1.x; a1.y += pt * v1.y; a1.z += pt * v1.z; a1.w += pt * v1.w;
  }
#pragma unroll
  for (int off = 8; off <= 32; off <<= 1) {
    a0.x += __shfl_xor(a0.x, off, 64);
    a0.y += __shfl_xor(a0.y, off, 64);
    a0.z += __shfl_xor(a0.z, off, 64);
    a0.w += __shfl_xor(a0.w, off, 64);
    a1.x += __shfl_xor(a1.x, off, 64);
    a1.y += __shfl_xor(a1.y, off, 64);
    a1.z += __shfl_xor(a1.z, off, 64);
    a1.w += __shfl_xor(a1.w, off, 64);
  }
  if (grp == 0) {
    float o[8] = {a0.x, a0.y, a0.z, a0.w, a1.x, a1.y, a1.z, a1.w};
    short8 hv, lv;
#pragma unroll
    for (int j = 0; j < 8; j++) {
      const float e = o[j] > 0.f ? o[j] : expf(o[j]) - 1.f;  // ELU
      short hh, ll;
      split_bf16(e, hh, ll);
      hv[j] = hh;
      lv[j] = ll;
    }
    const size_t base = (size_t)i * 512 + h * 64 + c8 * 8;
    *(short8*)&Hhi[base] = hv;
    *(short8*)&Hlo[base] = lv;
  }
}

// ---- gemm2: Wh2 = h @ W_out (split-bf16 MFMA, cols padded to 48);
//      fused s1b/s2b = Wh2 . a_out halves.
// 256 blocks x 16 rows; K=512 split 128-per-wave; A/B fragments read straight
// from L2 (16 rows x 64B contiguous segments -> fully coalesced); LDS only
// holds the 4-way cross-wave partial reduction. No staging barriers.
__global__ __launch_bounds__(256) void gemm2_mfma(
    const short* __restrict__ Hhi, const short* __restrict__ Hlo,
    const short* __restrict__ WOhi, const short* __restrict__ WOlo,
    const float* __restrict__ a_out,
    float* __restrict__ Wh2, float* __restrict__ s1b, float* __restrict__ s2b) {
  __shared__ float red[3][64][12];
  const int n0 = blockIdx.x * 16;
  const int tid = threadIdx.x;
  const int w = tid >> 6, L = tid & 63;
  const int r15 = L & 15;

  floatx4 acc[3];
#pragma unroll
  for (int f = 0; f < 3; f++) acc[f] = (floatx4){0.f, 0.f, 0.f, 0.f};

#pragma unroll
  for (int ks = 0; ks < 4; ks++) {
    const int koff = w * 128 + ks * 32 + (L >> 4) * 8;
    const short8 ahi = *(const short8*)&Hhi[(size_t)(n0 + r15) * 512 + koff];
    const short8 alo = *(const short8*)&Hlo[(size_t)(n0 + r15) * 512 + koff];
#pragma unroll
    for (int f = 0; f < 3; f++) {
      const short8 bhi = *(const short8*)&WOhi[(size_t)(f * 16 + r15) * 512 + koff];
      const short8 blo = *(const short8*)&WOlo[(size_t)(f * 16 + r15) * 512 + koff];
      acc[f] = __builtin_amdgcn_mfma_f32_16x16x32_bf16(ahi, bhi, acc[f], 0, 0, 0);
      acc[f] = __builtin_amdgcn_mfma_f32_16x16x32_bf16(ahi, blo, acc[f], 0, 0, 0);
      acc[f] = __builtin_amdgcn_mfma_f32_16x16x32_bf16(alo, bhi, acc[f], 0, 0, 0);
    }
  }

  if (w) {
#pragma unroll
    for (int f = 0; f < 3; f++)
#pragma unroll
      for (int r = 0; r < 4; r++) red[w - 1][L][f * 4 + r] = acc[f][r];
  }
  __syncthreads();
  if (w == 0) {
    const int q = L >> 4, c16 = r15;
    float a1v[3], a2v[3];
#pragma unroll
    for (int f = 0; f < 3; f++) {
      const int col = f * 16 + c16;
      a1v[f] = (col < NCLASS) ? a_out[col] : 0.f;
      a2v[f] = (col < NCLASS) ? a_out[NCLASS + col] : 0.f;
    }
    float p1[4] = {0.f, 0.f, 0.f, 0.f}, p2[4] = {0.f, 0.f, 0.f, 0.f};
#pragma unroll
    for (int f = 0; f < 3; f++)
#pragma unroll
      for (int r = 0; r < 4; r++) {
        const float vv = acc[f][r] + red[0][L][f * 4 + r] + red[1][L][f * 4 + r] +
                         red[2][L][f * 4 + r];
        const int col = f * 16 + c16;
        const int row = n0 + q * 4 + r;
        if (col < NCLASS) Wh2[(size_t)row * NCLASS + col] = vv;
        p1[r] += vv * a1v[f];
        p2[r] += vv * a2v[f];
      }
#pragma unroll
    for (int r = 0; r < 4; r++)
#pragma unroll
      for (int o = 1; o < 16; o <<= 1) {
        p1[r] += __shfl_xor(p1[r], o, 64);
        p2[r] += __shfl_xor(p2[r], o, 64);
      }
    if (c16 == 0) {
      const int row = n0 + q * 4;
#pragma unroll
      for (int r = 0; r < 4; r++) {
        s1b[row + r] = p1[r];
        s2b[row + r] = p2[r];
      }
    }
  }
}

// ----------------- layer-2 sparse attention + ELU + log_softmax -> out (fp32)
__global__ __launch_bounds__(256) void att2_kernel(const float* __restrict__ Wh2,
                                                   const float* __restrict__ s1b,
                                                   const float* __restrict__ s2b,
                                                   const int* __restrict__ cols,
                                                   const int* __restrict__ cnts,
                                                   float* __restrict__ out) {
  __shared__ float pj[4][64];
  __shared__ int jj[4][64];
  const int w = threadIdx.x >> 6, lane = threadIdx.x & 63;
  const int i = blockIdx.x * 4 + w;
  const int cnt = cnts[i];
  const float s1i = s1b[i];
  float e0 = -1e30f;
  int j0 = 0;
  if (lane < cnt) {
    j0 = cols[i * ELLW + lane];
    float t = s1i + s2b[j0];
    e0 = t > 0.f ? t : ALPHA * t;
  }
  const float m = wred_max(e0);
  float p = (lane < cnt) ? expf(e0 - m) : 0.f;
  const float S = wred_sum(p);
  p *= 1.f / S;
  pj[w][lane] = p;
  jj[w][lane] = (lane < cnt) ? j0 : 0;
  __syncthreads();
  float acc = 0.f;
  for (int t = 0; t < cnt; t++) {
    const float pt = pj[w][t];
    const int jt = jj[w][t];
    if (lane < NCLASS) acc += pt * Wh2[(size_t)jt * NCLASS + lane];
  }
  const float o = acc > 0.f ? acc : expf(acc) - 1.f;  // ELU
  const float vv = (lane < NCLASS) ? o : -1e30f;
  const float mm = wred_max(vv);
  const float ex = (lane < NCLASS) ? expf(o - mm) : 0.f;
  const float SS = wred_sum(ex);
  if (lane < NCLASS) out[(size_t)i * NCLASS + lane] = o - mm - logf(SS);
}

// ---------------------------------------------------------------------------
extern "C" void kernel_launch(void* const* d_in, const int* in_sizes, int n_in,
                              void* d_out, int out_size, void* d_ws, size_t ws_size,
                              hipStream_t stream) {
  const float* x       = (const float*)d_in[0];   // (4096, 512)
  const float* adj     = (const float*)d_in[1];   // (4096, 4096)
  const float* W_heads = (const float*)d_in[2];   // (8, 512, 64)
  const float* a_heads = (const float*)d_in[3];   // (8, 128, 1)
  const float* W_out   = (const float*)d_in[4];   // (512, 41)
  const float* a_out   = (const float*)d_in[5];   // (82, 1)
  float* out = (float*)d_out;                     // (4096, 41)

  // workspace layout (~29 MB)
  float* ws   = (float*)d_ws;
  float* Wh   = ws;                                  // 8*4096*64
  float* s1   = Wh + (size_t)NHEADS * N * NHID;      // 8*4096
  float* s2   = s1 + NHEADS * N;                     // 8*4096
  float* Wh2  = s2 + NHEADS * N;                     // 4096*41
  float* s1b  = Wh2 + (size_t)N * NCLASS;            // 4096
  float* s2b  = s1b + N;                             // 4096
  int* cnts   = (int*)(s2b + N);                     // 4096
  int* cols   = cnts + N;                            // 4096*64
  short* Xhi  = (short*)(cols + N * ELLW);           // 4096*512
  short* Xlo  = Xhi + (size_t)N * NFEAT;             // 4096*512
  short* Wthi = Xlo + (size_t)N * NFEAT;             // 8*64*512
  short* Wtlo = Wthi + (size_t)NHEADS * NHID * NFEAT;// 8*64*512
  short* WOhi = Wtlo + (size_t)NHEADS * NHID * NFEAT;// 48*512
  short* WOlo = WOhi + (size_t)NCPAD * 512;          // 48*512
  short* Hhi  = WOlo + (size_t)NCPAD * 512;          // 4096*512
  short* Hlo  = Hhi + (size_t)N * NFEAT;             // 4096*512

  hipLaunchKernelGGL(setup, dim3(6304), dim3(256), 0, stream,
                     x, W_heads, W_out, adj, Xhi, Xlo, Wthi, Wtlo, WOhi, WOlo, cols, cnts);
  hipLaunchKernelGGL(wh_gemm_mfma, dim3(NHEADS * N / 64), dim3(128), 0, stream,
                     Xhi, Xlo, Wthi, Wtlo, a_heads, Wh, s1, s2);
  hipLaunchKernelGGL(att1_kernel, dim3(NHEADS * N / 4), dim3(256), 0, stream,
                     Wh, s1, s2, cols, cnts, Hhi, Hlo);
  hipLaunchKernelGGL(gemm2_mfma, dim3(N / 16), dim3(256), 0, stream,
                     Hhi, Hlo, WOhi, WOlo, a_out, Wh2, s1b, s2b);
  hipLaunchKernelGGL(att2_kernel, dim3(N / 4), dim3(256), 0, stream,
                     Wh2, s1b, s2b, cols, cnts, out);
}